// Round 4
// baseline (139.383 us; speedup 1.0000x reference)
//
#include <hip/hip_runtime.h>
#include <cmath>

#define BB   512
#define NSV  128
#define NTRK 512
#define KK   8
#define HH   16
#define TPB  512
#define PSTR 20            // padded proj stride in LDS (keeps 16B alignment)

__device__ __forceinline__ float elu_f(float x) {
    return x > 0.0f ? x : expm1f(x);
}
__device__ __forceinline__ unsigned umin_u(unsigned a, unsigned b) { return a < b ? a : b; }
__device__ __forceinline__ unsigned med3u(unsigned a, unsigned b, unsigned c) {
    unsigned d;
    asm("v_med3_u32 %0, %1, %2, %3" : "=v"(d) : "v"(a), "v"(b), "v"(c));
    return d;
}

// ---------------- kernel 1: per-SV precompute into workspace ----------------
// svf_g[b*128+s][16], proj_g[b*128+s][16], hsq_g[b*128+s], wdiff_g[16][16]
__global__ __launch_bounds__(NSV) void precompute(
    const float* __restrict__ x_sv,
    const float* __restrict__ W1s, const float* __restrict__ b1s,
    const float* __restrict__ W2s, const float* __restrict__ b2s,
    const float* __restrict__ We,
    float* __restrict__ svf_g, float* __restrict__ proj_g,
    float* __restrict__ hsq_g, float* __restrict__ wdiff_g)
{
    const int b = blockIdx.x, s = threadIdx.x;

    const float* xp = x_sv + (size_t)(b * NSV + s) * 2;
    float x0 = xp[0], x1 = xp[1];
    float hb[HH];
    #pragma unroll
    for (int h = 0; h < HH; ++h)
        hb[h] = elu_f(x0 * W1s[h] + x1 * W1s[HH + h] + b1s[h]);

    float o[HH];
    float sq = 0.0f;
    #pragma unroll
    for (int h2 = 0; h2 < HH; ++h2) {
        float a = b2s[h2];
        #pragma unroll
        for (int h = 0; h < HH; ++h) a += hb[h] * W2s[h * HH + h2];
        o[h2] = a;
        sq += a * a;
    }

    float* sdst = svf_g + (size_t)(b * NSV + s) * HH;
    #pragma unroll
    for (int h4 = 0; h4 < 4; ++h4)
        *(float4*)&sdst[h4 * 4] = make_float4(o[h4*4], o[h4*4+1], o[h4*4+2], o[h4*4+3]);
    hsq_g[b * NSV + s] = 0.5f * sq;

    // proj[s][h] = o . We_bot[:,h]  (uses own row only — no LDS/sync needed)
    float* pdst = proj_g + (size_t)(b * NSV + s) * HH;
    #pragma unroll
    for (int h4 = 0; h4 < 4; ++h4) {
        float p[4];
        #pragma unroll
        for (int q = 0; q < 4; ++q) {
            int h = h4 * 4 + q;
            float a = 0.0f;
            #pragma unroll
            for (int j = 0; j < HH; ++j) a += o[j] * We[(HH + j) * HH + h];
            p[q] = a;
        }
        *(float4*)&pdst[h4 * 4] = make_float4(p[0], p[1], p[2], p[3]);
    }

    // Wdiff = We_top - We_bot; every block writes identical values (benign)
    #pragma unroll
    for (int r = 0; r < 2; ++r) {
        int e = s * 2 + r;                    // 0..255
        wdiff_g[e] = We[e] - We[NSV * 2 + e]; // We[j][h] - We[16+j][h], e=j*16+h
    }
}

// ---------------- kernel 2: track MLP + kNN + edge-max + pool ----------------
__global__ __launch_bounds__(TPB, 4) void fused_main(
    const float* __restrict__ x_trk,
    const float* __restrict__ W1t, const float* __restrict__ b1t,
    const float* __restrict__ W2t, const float* __restrict__ b2t,
    const float* __restrict__ be,  const float* __restrict__ Wo,
    const float* __restrict__ bo,
    const float* __restrict__ svf_g, const float* __restrict__ proj_g,
    const float* __restrict__ hsq_g, const float* __restrict__ wdiff_g,
    float* __restrict__ out)
{
    __shared__ float proj[NSV][PSTR];
    __shared__ float sred[TPB / 64];

    const int b = blockIdx.x, tid = threadIdx.x;

    // stage proj -> LDS (coalesced: 512 threads x float4 = 8 KB)
    {
        int s = tid >> 2, q = tid & 3;
        float4 p = *(const float4*)&proj_g[(size_t)(b * NSV + s) * HH + q * 4];
        *(float4*)&proj[s][q * 4] = p;
    }

    // track MLP (weights are wave-uniform -> scalar loads)
    float tf[HH], ntf[HH], htsq;
    {
        const float* xp = x_trk + (size_t)(b * NTRK + tid) * 8;
        float x[8];
        *(float4*)&x[0] = *(const float4*)&xp[0];
        *(float4*)&x[4] = *(const float4*)&xp[4];
        float hb[HH];
        #pragma unroll
        for (int h = 0; h < HH; ++h) {
            float a = b1t[h];
            #pragma unroll
            for (int i = 0; i < 8; ++i) a += x[i] * W1t[i * HH + h];
            hb[h] = elu_f(a);
        }
        float sq = 0.0f;
        #pragma unroll
        for (int h2 = 0; h2 < HH; ++h2) {
            float a = b2t[h2];
            #pragma unroll
            for (int h = 0; h < HH; ++h) a += hb[h] * W2t[h * HH + h2];
            tf[h2] = a;
            ntf[h2] = -a;
            sq += a * a;
        }
        htsq = 0.5f * sq;
    }

    unsigned k[KK];
    #pragma unroll
    for (int q = 0; q < KK; ++q) k[q] = 0xFFFFFFFFu;

    __syncthreads();   // proj staged

    // kNN: svf rows via SGPR (uniform addresses), zero LDS in the loop
    const float* __restrict__ svb = svf_g + (size_t)b * NSV * HH;
    const float* __restrict__ hsb = hsq_g + (size_t)b * NSV;
    #pragma unroll 2
    for (int s = 0; s < NSV; ++s) {
        const float* sp = svb + s * HH;      // uniform -> s_load_dwordx16
        float a0 = htsq, a1 = hsb[s];        // hsb[s] uniform -> s_load
        a0 = fmaf(ntf[0], sp[0], a0);
        a1 = fmaf(ntf[1], sp[1], a1);
        float a2 = ntf[2] * sp[2];
        float a3 = ntf[3] * sp[3];
        #pragma unroll
        for (int j = 4; j < HH; j += 4) {
            a0 = fmaf(ntf[j],     sp[j],     a0);
            a1 = fmaf(ntf[j + 1], sp[j + 1], a1);
            a2 = fmaf(ntf[j + 2], sp[j + 2], a2);
            a3 = fmaf(ntf[j + 3], sp[j + 3], a3);
        }
        float e = fmaxf((a0 + a1) + (a2 + a3), 0.0f);   // = d2/2, clamped
        unsigned v = (__float_as_uint(e) & 0xFFFFFF80u) | (unsigned)s;
        // parallel sorted-insert: depth-1 med3 network (all OLD k values)
        unsigned nk0 = umin_u(v, k[0]);
        unsigned nk1 = med3u(v, k[0], k[1]);
        unsigned nk2 = med3u(v, k[1], k[2]);
        unsigned nk3 = med3u(v, k[2], k[3]);
        unsigned nk4 = med3u(v, k[3], k[4]);
        unsigned nk5 = med3u(v, k[4], k[5]);
        unsigned nk6 = med3u(v, k[5], k[6]);
        unsigned nk7 = med3u(v, k[6], k[7]);
        k[0] = nk0; k[1] = nk1; k[2] = nk2; k[3] = nk3;
        k[4] = nk4; k[5] = nk5; k[6] = nk6; k[7] = nk7;
    }

    // epilogue
    float local;
    {
        float base[HH];
        #pragma unroll
        for (int h = 0; h < HH; ++h) {
            float a = be[h];
            #pragma unroll
            for (int j = 0; j < HH; ++j) a += tf[j] * wdiff_g[j * HH + h];
            base[h] = a;
        }
        float mx[HH];
        #pragma unroll
        for (int h = 0; h < HH; ++h) mx[h] = -INFINITY;
        #pragma unroll
        for (int q = 0; q < KK; ++q) {
            const float* pr = &proj[k[q] & 127u][0];
            #pragma unroll
            for (int h4 = 0; h4 < 4; ++h4) {
                float4 p = *(const float4*)&pr[h4 * 4];
                mx[h4 * 4 + 0] = fmaxf(mx[h4 * 4 + 0], p.x);
                mx[h4 * 4 + 1] = fmaxf(mx[h4 * 4 + 1], p.y);
                mx[h4 * 4 + 2] = fmaxf(mx[h4 * 4 + 2], p.z);
                mx[h4 * 4 + 3] = fmaxf(mx[h4 * 4 + 3], p.w);
            }
        }
        float acc = bo[0];
        #pragma unroll
        for (int h = 0; h < HH; ++h) acc += (base[h] + mx[h]) * Wo[h];
        local = 1.0f / (1.0f + expf(-acc));
    }

    // block mean-pool
    #pragma unroll
    for (int off = 32; off > 0; off >>= 1)
        local += __shfl_down(local, off, 64);
    if ((tid & 63) == 0) sred[tid >> 6] = local;
    __syncthreads();
    if (tid == 0) {
        float tot = 0.0f;
        #pragma unroll
        for (int w = 0; w < TPB / 64; ++w) tot += sred[w];
        out[b]      = tot * (1.0f / NTRK);
        out[BB + b] = (float)b;
    }
}

extern "C" void kernel_launch(void* const* d_in, const int* in_sizes, int n_in,
                              void* d_out, int out_size, void* d_ws, size_t ws_size,
                              hipStream_t stream) {
    const float* x_sv  = (const float*)d_in[0];
    const float* x_trk = (const float*)d_in[1];
    const float* W1s = (const float*)d_in[4];
    const float* b1s = (const float*)d_in[5];
    const float* W2s = (const float*)d_in[6];
    const float* b2s = (const float*)d_in[7];
    const float* W1t = (const float*)d_in[8];
    const float* b1t = (const float*)d_in[9];
    const float* W2t = (const float*)d_in[10];
    const float* b2t = (const float*)d_in[11];
    const float* We  = (const float*)d_in[12];
    const float* be  = (const float*)d_in[13];
    const float* Wo  = (const float*)d_in[14];
    const float* bo  = (const float*)d_in[15];
    float* out = (float*)d_out;

    float* svf_g  = (float*)d_ws;                 // 512*128*16 f = 4 MB
    float* proj_g = svf_g  + (size_t)BB * NSV * HH;
    float* hsq_g  = proj_g + (size_t)BB * NSV * HH;
    float* wdiff_g = hsq_g + (size_t)BB * NSV;    // 256 f

    precompute<<<BB, NSV, 0, stream>>>(x_sv, W1s, b1s, W2s, b2s, We,
                                       svf_g, proj_g, hsq_g, wdiff_g);
    fused_main<<<BB, TPB, 0, stream>>>(x_trk, W1t, b1t, W2t, b2t,
                                       be, Wo, bo,
                                       svf_g, proj_g, hsq_g, wdiff_g, out);
}

// Round 5
// 132.684 us; speedup vs baseline: 1.0505x; 1.0505x over previous
//
#include <hip/hip_runtime.h>
#include <cmath>

#define BB   512
#define NSV  128
#define NTRK 512
#define KK   8
#define HH   16
#define TPB  512
#define PSTR 20            // padded proj stride in LDS

__device__ __forceinline__ float elu_f(float x) {
    return x > 0.0f ? x : expm1f(x);
}
__device__ __forceinline__ unsigned umin_u(unsigned a, unsigned b) { return a < b ? a : b; }
__device__ __forceinline__ unsigned med3u(unsigned a, unsigned b, unsigned c) {
    unsigned d;
    asm("v_med3_u32 %0, %1, %2, %3" : "=v"(d) : "v"(a), "v"(b), "v"(c));
    return d;
}

// ---------------- kernel 1: per-SV precompute into workspace ----------------
// svf_g[b*128+s][16], proj_g[b*128+s][16], hsq_g[b*128+s], uc_g[17] = {u[16], c0}
__global__ __launch_bounds__(NSV) void precompute(
    const float* __restrict__ x_sv,
    const float* __restrict__ W1s, const float* __restrict__ b1s,
    const float* __restrict__ W2s, const float* __restrict__ b2s,
    const float* __restrict__ We,  const float* __restrict__ be,
    const float* __restrict__ Wo,  const float* __restrict__ bo,
    float* __restrict__ svf_g, float* __restrict__ proj_g,
    float* __restrict__ hsq_g, float* __restrict__ uc_g)
{
    const int b = blockIdx.x, s = threadIdx.x;

    const float* xp = x_sv + (size_t)(b * NSV + s) * 2;
    float x0 = xp[0], x1 = xp[1];
    float hb[HH];
    #pragma unroll
    for (int h = 0; h < HH; ++h)
        hb[h] = elu_f(x0 * W1s[h] + x1 * W1s[HH + h] + b1s[h]);

    float o[HH];
    float sq = 0.0f;
    #pragma unroll
    for (int h2 = 0; h2 < HH; ++h2) {
        float a = b2s[h2];
        #pragma unroll
        for (int h = 0; h < HH; ++h) a += hb[h] * W2s[h * HH + h2];
        o[h2] = a;
        sq += a * a;
    }

    float* sdst = svf_g + (size_t)(b * NSV + s) * HH;
    #pragma unroll
    for (int h4 = 0; h4 < 4; ++h4)
        *(float4*)&sdst[h4 * 4] = make_float4(o[h4*4], o[h4*4+1], o[h4*4+2], o[h4*4+3]);
    hsq_g[b * NSV + s] = 0.5f * sq;

    // proj[s][h] = o . We_bot[:,h]
    float* pdst = proj_g + (size_t)(b * NSV + s) * HH;
    #pragma unroll
    for (int h4 = 0; h4 < 4; ++h4) {
        float p[4];
        #pragma unroll
        for (int q = 0; q < 4; ++q) {
            int h = h4 * 4 + q;
            float a = 0.0f;
            #pragma unroll
            for (int j = 0; j < HH; ++j) a += o[j] * We[(HH + j) * HH + h];
            p[q] = a;
        }
        *(float4*)&pdst[h4 * 4] = make_float4(p[0], p[1], p[2], p[3]);
    }

    // u[j] = sum_h (We_top[j][h]-We_bot[j][h]) * Wo[h];  c0 = bo + be.Wo
    if (b == 0) {
        if (s < HH) {
            float a = 0.0f;
            #pragma unroll
            for (int h = 0; h < HH; ++h)
                a += (We[s * HH + h] - We[(HH + s) * HH + h]) * Wo[h];
            uc_g[s] = a;
        } else if (s == HH) {
            float a = bo[0];
            #pragma unroll
            for (int h = 0; h < HH; ++h) a += be[h] * Wo[h];
            uc_g[HH] = a;
        }
    }
}

// ---------------- kernel 2: track MLP + kNN + edge-max + pool ----------------
__global__ __launch_bounds__(TPB, 4) void fused_main(
    const float* __restrict__ x_trk,
    const float* __restrict__ W1t, const float* __restrict__ b1t,
    const float* __restrict__ W2t, const float* __restrict__ b2t,
    const float* __restrict__ Wo,
    const float* __restrict__ svf_g, const float* __restrict__ proj_g,
    const float* __restrict__ hsq_g, const float* __restrict__ uc_g,
    float* __restrict__ out)
{
    __shared__ float proj[NSV][PSTR];
    __shared__ float sred[TPB / 64];

    const int b = blockIdx.x, tid = threadIdx.x;

    // stage proj -> LDS (coalesced)
    {
        int s = tid >> 2, q = tid & 3;
        float4 p = *(const float4*)&proj_g[(size_t)(b * NSV + s) * HH + q * 4];
        *(float4*)&proj[s][q * 4] = p;
    }

    // track MLP (uniform weights -> scalar loads)
    float tf[HH], ntf[HH], htsq;
    {
        const float* xp = x_trk + (size_t)(b * NTRK + tid) * 8;
        float x[8];
        *(float4*)&x[0] = *(const float4*)&xp[0];
        *(float4*)&x[4] = *(const float4*)&xp[4];
        float hb[HH];
        #pragma unroll
        for (int h = 0; h < HH; ++h) {
            float a = b1t[h];
            #pragma unroll
            for (int i = 0; i < 8; ++i) a += x[i] * W1t[i * HH + h];
            hb[h] = elu_f(a);
        }
        float sq = 0.0f;
        #pragma unroll
        for (int h2 = 0; h2 < HH; ++h2) {
            float a = b2t[h2];
            #pragma unroll
            for (int h = 0; h < HH; ++h) a += hb[h] * W2t[h * HH + h2];
            tf[h2] = a;
            ntf[h2] = -a;
            sq += a * a;
        }
        htsq = 0.5f * sq;
    }

    unsigned k[KK];
    #pragma unroll
    for (int q = 0; q < KK; ++q) k[q] = 0xFFFFFFFFu;

    __syncthreads();   // proj staged

    // ---- kNN with explicit software pipeline over uniform (scalar) rows ----
    const float* __restrict__ svb = svf_g + (size_t)b * NSV * HH;
    const float* __restrict__ hsb = hsq_g + (size_t)b * NSV;

    float pa[HH], pb[HH], ha, hbv;

    #define LOADROW(buf, hv, idx)                         \
        do {                                              \
            const float* _sp = svb + (idx) * HH;          \
            _Pragma("unroll")                             \
            for (int _j = 0; _j < HH; ++_j) buf[_j] = _sp[_j]; \
            hv = hsb[idx];                                \
        } while (0)

    #define BODY(buf, hv, idx)                                        \
        do {                                                          \
            float a0 = fmaf(ntf[0], buf[0], htsq);                    \
            float a1 = fmaf(ntf[1], buf[1], hv);                      \
            float a2 = ntf[2] * buf[2];                               \
            float a3 = ntf[3] * buf[3];                               \
            _Pragma("unroll")                                         \
            for (int _j = 4; _j < HH; _j += 4) {                      \
                a0 = fmaf(ntf[_j],     buf[_j],     a0);              \
                a1 = fmaf(ntf[_j + 1], buf[_j + 1], a1);              \
                a2 = fmaf(ntf[_j + 2], buf[_j + 2], a2);              \
                a3 = fmaf(ntf[_j + 3], buf[_j + 3], a3);              \
            }                                                         \
            float e = fmaxf((a0 + a1) + (a2 + a3), 0.0f);             \
            unsigned v = (__float_as_uint(e) & 0xFFFFFF80u) | (unsigned)(idx); \
            unsigned nk0 = umin_u(v, k[0]);                           \
            unsigned nk1 = med3u(v, k[0], k[1]);                      \
            unsigned nk2 = med3u(v, k[1], k[2]);                      \
            unsigned nk3 = med3u(v, k[2], k[3]);                      \
            unsigned nk4 = med3u(v, k[3], k[4]);                      \
            unsigned nk5 = med3u(v, k[4], k[5]);                      \
            unsigned nk6 = med3u(v, k[5], k[6]);                      \
            unsigned nk7 = med3u(v, k[6], k[7]);                      \
            k[0] = nk0; k[1] = nk1; k[2] = nk2; k[3] = nk3;           \
            k[4] = nk4; k[5] = nk5; k[6] = nk6; k[7] = nk7;           \
        } while (0)

    LOADROW(pa, ha, 0);
    LOADROW(pb, hbv, 1);
    for (int s = 0; s < NSV - 2; s += 2) {
        BODY(pa, ha, s);
        LOADROW(pa, ha, s + 2);        // issued one full body ahead of use
        BODY(pb, hbv, s + 1);
        LOADROW(pb, hbv, s + 3);
    }
    BODY(pa, ha, NSV - 2);
    BODY(pb, hbv, NSV - 1);

    #undef LOADROW
    #undef BODY

    // ---- epilogue: acc = c0 + tf.u + sum_h max_k(proj)[h] * Wo[h] ----
    float local;
    {
        float acc = uc_g[HH];                    // c0 (uniform -> scalar)
        #pragma unroll
        for (int j = 0; j < HH; ++j) acc = fmaf(tf[j], uc_g[j], acc);

        float mx[HH];
        #pragma unroll
        for (int h = 0; h < HH; ++h) mx[h] = -INFINITY;
        #pragma unroll
        for (int q = 0; q < KK; ++q) {
            const float* pr = &proj[k[q] & 127u][0];
            #pragma unroll
            for (int h4 = 0; h4 < 4; ++h4) {
                float4 p = *(const float4*)&pr[h4 * 4];
                mx[h4 * 4 + 0] = fmaxf(mx[h4 * 4 + 0], p.x);
                mx[h4 * 4 + 1] = fmaxf(mx[h4 * 4 + 1], p.y);
                mx[h4 * 4 + 2] = fmaxf(mx[h4 * 4 + 2], p.z);
                mx[h4 * 4 + 3] = fmaxf(mx[h4 * 4 + 3], p.w);
            }
        }
        #pragma unroll
        for (int h = 0; h < HH; ++h) acc = fmaf(mx[h], Wo[h], acc);
        local = 1.0f / (1.0f + expf(-acc));
    }

    // ---- block mean-pool ----
    #pragma unroll
    for (int off = 32; off > 0; off >>= 1)
        local += __shfl_down(local, off, 64);
    if ((tid & 63) == 0) sred[tid >> 6] = local;
    __syncthreads();
    if (tid == 0) {
        float tot = 0.0f;
        #pragma unroll
        for (int w = 0; w < TPB / 64; ++w) tot += sred[w];
        out[b]      = tot * (1.0f / NTRK);
        out[BB + b] = (float)b;
    }
}

extern "C" void kernel_launch(void* const* d_in, const int* in_sizes, int n_in,
                              void* d_out, int out_size, void* d_ws, size_t ws_size,
                              hipStream_t stream) {
    const float* x_sv  = (const float*)d_in[0];
    const float* x_trk = (const float*)d_in[1];
    const float* W1s = (const float*)d_in[4];
    const float* b1s = (const float*)d_in[5];
    const float* W2s = (const float*)d_in[6];
    const float* b2s = (const float*)d_in[7];
    const float* W1t = (const float*)d_in[8];
    const float* b1t = (const float*)d_in[9];
    const float* W2t = (const float*)d_in[10];
    const float* b2t = (const float*)d_in[11];
    const float* We  = (const float*)d_in[12];
    const float* be  = (const float*)d_in[13];
    const float* Wo  = (const float*)d_in[14];
    const float* bo  = (const float*)d_in[15];
    float* out = (float*)d_out;

    float* svf_g  = (float*)d_ws;                  // 512*128*16 f = 4 MB
    float* proj_g = svf_g  + (size_t)BB * NSV * HH;
    float* hsq_g  = proj_g + (size_t)BB * NSV * HH;
    float* uc_g   = hsq_g  + (size_t)BB * NSV;     // 17 floats

    precompute<<<BB, NSV, 0, stream>>>(x_sv, W1s, b1s, W2s, b2s, We, be, Wo, bo,
                                       svf_g, proj_g, hsq_g, uc_g);
    fused_main<<<BB, TPB, 0, stream>>>(x_trk, W1t, b1t, W2t, b2t, Wo,
                                       svf_g, proj_g, hsq_g, uc_g, out);
}